// Round 10
// baseline (361.019 us; speedup 1.0000x reference)
//
#include <hip/hip_runtime.h>
#include <math.h>

typedef _Float16 f16;
typedef _Float16 f16x8 __attribute__((ext_vector_type(8)));
typedef float f32x4 __attribute__((ext_vector_type(4)));

#define KCODES 8192
#define DDIM   256
#define NTOT   16384
#define QT     32      // queries per block (2 blocks/CU -> 4 waves/SIMD)
#define NKT    32      // k-tiles of 256 codes
#define NCH    256     // total 32KB chunks = NKT*8
#define CHB    32768   // chunk image bytes: 2 planes * 256 codes * 32 d * 2B

#define F16_MIN_NORMAL 6.103515625e-05f

// ws layout: [0] loss | +256B e2[8192] f32 | z2[16384] f32 | +131072B emb-plane image (8 MB)

// z2[n]: exact (fp64) sum of fp32 squares, rounded once (rounds 2-9 verified). Also zeroes loss.
__global__ void z2_kernel(const float* __restrict__ z, float* __restrict__ z2out,
                          float* __restrict__ loss) {
    int n  = blockIdx.x * 256 + threadIdx.x;
    if (n == 0) loss[0] = 0.0f;
    int b  = n >> 10;
    int hw = n & 1023;
    const float* base = z + (size_t)b * DDIM * 1024 + hw;
    double acc = 0.0;
    #pragma unroll 8
    for (int d = 0; d < 256; ++d) {
        float v  = base[(size_t)d * 1024];
        float sq = __fmul_rn(v, v);
        acc += (double)sq;
    }
    z2out[n] = (float)acc;
}

// split emb into 2 fp16 planes (pre-scaled by 2^13) as the swizzled image; fused e2.
// Image layout bit-identical to rounds 3-9.
__global__ void esplit_kernel(const float* __restrict__ emb, char* __restrict__ img,
                              float* __restrict__ e2out) {
    __shared__ double part[4];
    int c = blockIdx.x, d = threadIdx.x;
    float ev = emb[(size_t)c * 256 + d];
    double sq = (double)__fmul_rn(ev, ev);
    #pragma unroll
    for (int off = 32; off > 0; off >>= 1) sq += __shfl_down(sq, off, 64);
    if ((d & 63) == 0) part[d >> 6] = sq;
    __syncthreads();
    if (d == 0) e2out[c] = (float)(part[0] + part[1] + part[2] + part[3]);
    float e = ev * 8192.0f;                               // exact pow2 scale
    float eh = 0.0f;
    if (fabsf(e) >= F16_MIN_NORMAL) eh = (float)(f16)e;   // normal-or-zero hi plane
    f16 ehh = (f16)eh;
    f16 emm = (f16)((e - eh) * 2048.0f);                  // residual scaled 2^11
    int kt = c >> 8, ch = d >> 5, ci = c & 255, dp = d & 31;
    char* p = img + (size_t)(kt * 8 + ch) * CHB;
    int off2 = (ci * 64 + dp * 2) ^ ((ci & 7) << 4);      // XOR swizzle (bits 4-6)
    *(f16*)(p + off2) = ehh;
    *(f16*)(p + 16384 + off2) = emm;
}

// QT=32 per block, 8 waves, grid 512 -> 2 blocks/CU = 4 waves/SIMD. Two independent
// blocks interleave: one block's LDS/score phase hides under the other's MFMA burst.
// Per-(q,code) computation bit-identical to rounds 3-9 (same fragments/order/rounding).
__launch_bounds__(512, 4)
__global__ void vq_main(const float* __restrict__ z, const float* __restrict__ emb,
                        const float* __restrict__ e2w, const float* __restrict__ z2w,
                        const char* __restrict__ img, float* __restrict__ loss_accum,
                        float* __restrict__ out0, float* __restrict__ out1) {
    __shared__ __align__(16) char zsH[16384];     // z hi plane  [32 q][256 d] f16, swizzled
    __shared__ __align__(16) char zsM[16384];     // z mid plane (scaled 2^11)
    __shared__ float redv[8][QT];
    __shared__ int   redi[8][QT];
    __shared__ int   bidx[QT];
    __shared__ float wsum[8];

    const int tid  = threadIdx.x;
    const int w    = tid >> 6;
    const int lane = tid & 63;
    const int l15  = lane & 15;
    const int lg   = lane >> 4;
    const int nb   = blockIdx.x * QT;
    const int b    = nb >> 10;
    const int hw0  = nb & 1023;

    // per-lane B read offsets (fixed per chunk; same formula as rounds 3-9)
    int boff[2];
    #pragma unroll
    for (int n = 0; n < 2; ++n) {
        const int c = w * 32 + n * 16 + l15;
        boff[n] = (c * 64 + lg * 16) ^ ((c & 7) << 4);
    }

    // ---- build z fp16 planes in LDS (b128 writes; values/offsets bit-identical) ----
    {
        const int q = tid & 31, dg = tid >> 5;    // dg 0..15 -> 16 d per thread
        #pragma unroll
        for (int g = 0; g < 2; ++g) {
            const int d0 = dg * 16 + g * 8;       // 8 consecutive d
            f16 hv[8], mv[8];
            #pragma unroll
            for (int j = 0; j < 8; ++j) {
                float zv = z[(size_t)(b * 256 + d0 + j) * 1024 + hw0 + q];
                float zh = 0.0f;
                if (fabsf(zv) >= F16_MIN_NORMAL) zh = (float)(f16)zv;
                hv[j] = (f16)zh;
                mv[j] = (f16)((zv - zh) * 2048.0f);
            }
            const int off = (q * 512 + d0 * 2) ^ ((q & 7) << 4);  // 16B-aligned
            *(f16x8*)(zsH + off) = *(const f16x8*)hv;
            *(f16x8*)(zsM + off) = *(const f16x8*)mv;
        }
    }

    float z2r[2][4];
    #pragma unroll
    for (int m = 0; m < 2; ++m)
        #pragma unroll
        for (int r = 0; r < 4; ++r)
            z2r[m][r] = z2w[nb + m * 16 + lg * 4 + r];

    float bestv[2][4];
    int   besti[2][4];
    #pragma unroll
    for (int m = 0; m < 2; ++m)
        #pragma unroll
        for (int r = 0; r < 4; ++r) { bestv[m][r] = INFINITY; besti[m][r] = 0; }

    // B register double-buffer: prefetch chunk 0
    f16x8 bhA[2], bmA[2], bhB[2], bmB[2];
    #pragma unroll
    for (int n = 0; n < 2; ++n) {
        bhA[n] = *(const f16x8*)(img + boff[n]);
        bmA[n] = *(const f16x8*)(img + 16384 + boff[n]);
    }

    __syncthreads();   // z planes published

// one pipeline phase: prefetch B(t+1) into NXT regs, read A(t) from static z-LDS, MFMA with CUR
#define PHASE(CH, CURH, CURM, NXTH, NXTM)                                                  \
    {                                                                                      \
        const int t  = kt * 8 + (CH);                                                      \
        const int tn = (t + 1 < NCH) ? (t + 1) : 0;                                        \
        const char* nbase = img + (size_t)tn * CHB;                                        \
        _Pragma("unroll")                                                                  \
        for (int n = 0; n < 2; ++n) {                                                      \
            NXTH[n] = *(const f16x8*)(nbase + boff[n]);                                    \
            NXTM[n] = *(const f16x8*)(nbase + 16384 + boff[n]);                            \
        }                                                                                  \
        f16x8 ah[2], am[2];                                                                \
        _Pragma("unroll")                                                                  \
        for (int m = 0; m < 2; ++m) {                                                      \
            const int q = m * 16 + l15;                                                    \
            const int off = (q * 512 + ((CH) * 32 + lg * 8) * 2) ^ ((q & 7) << 4);         \
            ah[m] = *(const f16x8*)(zsH + off);                                            \
            am[m] = *(const f16x8*)(zsM + off);                                            \
        }                                                                                  \
        __builtin_amdgcn_s_setprio(1);                                                     \
        _Pragma("unroll")                                                                  \
        for (int m = 0; m < 2; ++m)                                                        \
            _Pragma("unroll")                                                              \
            for (int n = 0; n < 2; ++n) {                                                  \
                a1[m][n] = __builtin_amdgcn_mfma_f32_16x16x32_f16(ah[m], CURH[n], a1[m][n], 0, 0, 0); \
                a2[m][n] = __builtin_amdgcn_mfma_f32_16x16x32_f16(ah[m], CURM[n], a2[m][n], 0, 0, 0); \
                a2[m][n] = __builtin_amdgcn_mfma_f32_16x16x32_f16(am[m], CURH[n], a2[m][n], 0, 0, 0); \
                a3[m][n] = __builtin_amdgcn_mfma_f32_16x16x32_f16(am[m], CURM[n], a3[m][n], 0, 0, 0); \
            }                                                                              \
        __builtin_amdgcn_s_setprio(0);                                                     \
    }

    for (int kt = 0; kt < NKT; ++kt) {
        f32x4 a1[2][2], a2[2][2], a3[2][2];
        const f32x4 vz = {0.0f, 0.0f, 0.0f, 0.0f};
        #pragma unroll
        for (int m = 0; m < 2; ++m)
            #pragma unroll
            for (int n = 0; n < 2; ++n) { a1[m][n] = vz; a2[m][n] = vz; a3[m][n] = vz; }

        float e2v[2];
        #pragma unroll
        for (int n = 0; n < 2; ++n)
            e2v[n] = e2w[kt * 256 + w * 32 + n * 16 + l15];

        PHASE(0, bhA, bmA, bhB, bmB)
        PHASE(1, bhB, bmB, bhA, bmA)
        PHASE(2, bhA, bmA, bhB, bmB)
        PHASE(3, bhB, bmB, bhA, bmA)
        PHASE(4, bhA, bmA, bhB, bmB)
        PHASE(5, bhB, bmB, bhA, bmA)
        PHASE(6, bhA, bmA, bhB, bmB)
        PHASE(7, bhB, bmB, bhA, bmA)

        // ---- per-k-tile score + argmin (bit-identical rounding to rounds 2-9) ----
        #pragma unroll
        for (int m = 0; m < 2; ++m)
            #pragma unroll
            for (int n = 0; n < 2; ++n) {
                const int code = kt * 256 + w * 32 + n * 16 + l15;
                #pragma unroll
                for (int r = 0; r < 4; ++r) {
                    float rr = fmaf(a3[m][n][r], 0x1p-11f, a2[m][n][r]);
                    rr = fmaf(rr, 0x1p-11f, a1[m][n][r]);           // dot * 2^13
                    float tt = fmaf(rr, -0x1p-12f, z2r[m][r]);      // = fl(z2 - 2*dot), single round
                    float s  = __fadd_rn(tt, e2v[n]);
                    if (s < bestv[m][r]) { bestv[m][r] = s; besti[m][r] = code; }
                }
            }

        // PACING barrier every 2 k-tiles (round-9 verified: bounds drift, L2 stays hot;
        // the OTHER co-resident block is unsynced -> its MFMA covers our LDS/score phase).
        if (kt & 1) __builtin_amdgcn_s_barrier();
    }
#undef PHASE

    // ---- cross-lane argmin within each 16-lane column group ----
    #pragma unroll
    for (int m = 0; m < 2; ++m)
        #pragma unroll
        for (int r = 0; r < 4; ++r) {
            float v = bestv[m][r]; int idx = besti[m][r];
            #pragma unroll
            for (int dlt = 1; dlt < 16; dlt <<= 1) {
                float v2 = __shfl_xor(v, dlt, 64);
                int   i2 = __shfl_xor(idx, dlt, 64);
                if (v2 < v || (v2 == v && i2 < idx)) { v = v2; idx = i2; }
            }
            if (l15 == 0) {
                const int q = m * 16 + lg * 4 + r;   // 0..31
                redv[w][q] = v; redi[w][q] = idx;
            }
        }
    __syncthreads();
    if (tid < QT) {
        float bv = redv[0][tid]; int bi = redi[0][tid];
        #pragma unroll
        for (int ww = 1; ww < 8; ++ww) {
            float v = redv[ww][tid]; int ii = redi[ww][tid];
            if (v < bv || (v == bv && ii < bi)) { bv = v; bi = ii; }
        }
        bidx[tid] = bi;
        out1[nb + tid] = (float)bi;
    }
    __syncthreads();

    // ---- fused epilogue: quantized_st + commit-loss partial (float4 erow reads) ----
    {
        const int q = tid & 31, dg = tid >> 5;    // dg 0..15 -> 16 consecutive d
        const int myidx = bidx[q];
        const float* erow = emb + (size_t)myidx * 256;
        float lsum = 0.0f;
        #pragma unroll
        for (int g = 0; g < 4; ++g) {
            const int d0 = dg * 16 + g * 4;
            float4 qv4 = *(const float4*)(erow + d0);
            #pragma unroll
            for (int j = 0; j < 4; ++j) {
                const int d = d0 + j;
                const size_t gi = (size_t)(b * 256 + d) * 1024 + hw0 + q;
                float zv = z[gi];
                float qv = (&qv4.x)[j];
                out0[gi] = zv + (qv - zv);
                float e = zv - qv;
                lsum += e * e;
            }
        }
        #pragma unroll
        for (int off = 32; off > 0; off >>= 1) lsum += __shfl_down(lsum, off, 64);
        if (lane == 0) wsum[w] = lsum;
        __syncthreads();
        if (tid == 0) {
            float s = 0.0f;
            #pragma unroll
            for (int i = 0; i < 8; ++i) s += wsum[i];
            atomicAdd(loss_accum, s);
        }
    }
}

__global__ void loss_final(const float* __restrict__ loss_accum, float* __restrict__ out2) {
    out2[0] = loss_accum[0] * (1.0f / 4194304.0f);
}

extern "C" void kernel_launch(void* const* d_in, const int* in_sizes, int n_in,
                              void* d_out, int out_size, void* d_ws, size_t ws_size,
                              hipStream_t stream) {
    (void)in_sizes; (void)n_in; (void)out_size; (void)ws_size;
    const float* z   = (const float*)d_in[0];   // (16,256,32,32)
    const float* emb = (const float*)d_in[1];   // (8192,256)
    float* ws_f = (float*)d_ws;
    char*  wsb  = (char*)d_ws;
    float* loss = ws_f;                          // [0]
    float* e2   = ws_f + 64;                     // 8192 f32
    float* z2   = ws_f + 64 + KCODES;            // 16384 f32
    char*  img  = wsb + 131072;                  // 8 MB fp16-plane image
    float* out0 = (float*)d_out;                 // quantized_st: 4,194,304
    float* out1 = out0 + (size_t)4194304;        // indices:      16,384
    float* out2 = out1 + (size_t)16384;          // commit_loss:  1

    esplit_kernel<<<KCODES, 256, 0, stream>>>(emb, img, e2);
    z2_kernel<<<NTOT / 256, 256, 0, stream>>>(z, z2, loss);
    vq_main<<<NTOT / QT, 512, 0, stream>>>(z, emb, e2, z2, img, loss, out0, out1);
    loss_final<<<1, 1, 0, stream>>>(loss, out2);
}

// Round 11
// 267.915 us; speedup vs baseline: 1.3475x; 1.3475x over previous
//
#include <hip/hip_runtime.h>
#include <math.h>

typedef _Float16 f16;
typedef _Float16 f16x8 __attribute__((ext_vector_type(8)));
typedef float f32x4 __attribute__((ext_vector_type(4)));

#define KCODES 8192
#define DDIM   256
#define NTOT   16384
#define QT     32      // queries per block; grid 512 = 2 lockstep generations at 1 block/CU
#define NKT    32      // k-tiles of 256 codes
#define NCH    256     // total 32KB chunks = NKT*8
#define CHB    32768   // chunk image bytes: 2 planes * 256 codes * 32 d * 2B

#define F16_MIN_NORMAL 6.103515625e-05f

// ws layout: [0] loss | +256B e2[8192] f32 | z2[16384] f32 | +131072B emb-plane image (8 MB)

// z2[n]: exact (fp64) sum of fp32 squares, rounded once (rounds 2-10 verified). Also zeroes loss.
__global__ void z2_kernel(const float* __restrict__ z, float* __restrict__ z2out,
                          float* __restrict__ loss) {
    int n  = blockIdx.x * 256 + threadIdx.x;
    if (n == 0) loss[0] = 0.0f;
    int b  = n >> 10;
    int hw = n & 1023;
    const float* base = z + (size_t)b * DDIM * 1024 + hw;
    double acc = 0.0;
    #pragma unroll 8
    for (int d = 0; d < 256; ++d) {
        float v  = base[(size_t)d * 1024];
        float sq = __fmul_rn(v, v);
        acc += (double)sq;
    }
    z2out[n] = (float)acc;
}

// split emb into 2 fp16 planes (pre-scaled by 2^13) as the swizzled image; fused e2.
// Image layout bit-identical to rounds 3-10.
__global__ void esplit_kernel(const float* __restrict__ emb, char* __restrict__ img,
                              float* __restrict__ e2out) {
    __shared__ double part[4];
    int c = blockIdx.x, d = threadIdx.x;
    float ev = emb[(size_t)c * 256 + d];
    double sq = (double)__fmul_rn(ev, ev);
    #pragma unroll
    for (int off = 32; off > 0; off >>= 1) sq += __shfl_down(sq, off, 64);
    if ((d & 63) == 0) part[d >> 6] = sq;
    __syncthreads();
    if (d == 0) e2out[c] = (float)(part[0] + part[1] + part[2] + part[3]);
    float e = ev * 8192.0f;                               // exact pow2 scale
    float eh = 0.0f;
    if (fabsf(e) >= F16_MIN_NORMAL) eh = (float)(f16)e;   // normal-or-zero hi plane
    f16 ehh = (f16)eh;
    f16 emm = (f16)((e - eh) * 2048.0f);                  // residual scaled 2^11
    int kt = c >> 8, ch = d >> 5, ci = c & 255, dp = d & 31;
    char* p = img + (size_t)(kt * 8 + ch) * CHB;
    int off2 = (ci * 64 + dp * 2) ^ ((ci & 7) << 4);      // XOR swizzle (bits 4-6)
    *(f16*)(p + off2) = ehh;
    *(f16*)(p + 16384 + off2) = emm;
}

// QT=32, 8 waves, LDS sized to 86 KB -> exactly 1 block/CU (2 waves/SIMD), grid 512 runs
// as two lockstep generations (L2 stream stays hot, round-6/9-verified pacing).
// NEW: A-register double-buffer (ILP): phase t issues B(t+1) global loads and A(ch+1)
// ds_reads, MFMAs consume registers loaded in phase t-1 -> latency hides under MFMA.
// QT=32 gives the VGPR headroom round 8 lacked (R10 measured 64 VGPR).
__launch_bounds__(512, 2)
__global__ void vq_main(const float* __restrict__ z, const float* __restrict__ emb,
                        const float* __restrict__ e2w, const float* __restrict__ z2w,
                        const char* __restrict__ img, float* __restrict__ loss_accum,
                        float* __restrict__ out0, float* __restrict__ out1) {
    // 41 KB per plane (only first 16 KB used) -> 86 KB/block -> 1 block/CU occupancy cap
    __shared__ __align__(16) char zsH[41984];     // z hi plane  [32 q][256 d] f16, swizzled
    __shared__ __align__(16) char zsM[41984];     // z mid plane (scaled 2^11)
    __shared__ float redv[8][QT];
    __shared__ int   redi[8][QT];
    __shared__ int   bidx[QT];
    __shared__ float wsum[8];

    const int tid  = threadIdx.x;
    const int w    = tid >> 6;
    const int lane = tid & 63;
    const int l15  = lane & 15;
    const int lg   = lane >> 4;
    const int nb   = blockIdx.x * QT;
    const int b    = nb >> 10;
    const int hw0  = nb & 1023;

    // per-lane B read offsets (fixed per chunk; same formula as rounds 3-10)
    int boff[2];
    #pragma unroll
    for (int n = 0; n < 2; ++n) {
        const int c = w * 32 + n * 16 + l15;
        boff[n] = (c * 64 + lg * 16) ^ ((c & 7) << 4);
    }

    // ---- build z fp16 planes in LDS (b128 writes; values/offsets bit-identical) ----
    {
        const int q = tid & 31, dg = tid >> 5;    // dg 0..15 -> 16 d per thread
        #pragma unroll
        for (int g = 0; g < 2; ++g) {
            const int d0 = dg * 16 + g * 8;       // 8 consecutive d
            f16 hv[8], mv[8];
            #pragma unroll
            for (int j = 0; j < 8; ++j) {
                float zv = z[(size_t)(b * 256 + d0 + j) * 1024 + hw0 + q];
                float zh = 0.0f;
                if (fabsf(zv) >= F16_MIN_NORMAL) zh = (float)(f16)zv;
                hv[j] = (f16)zh;
                mv[j] = (f16)((zv - zh) * 2048.0f);
            }
            const int off = (q * 512 + d0 * 2) ^ ((q & 7) << 4);  // 16B-aligned
            *(f16x8*)(zsH + off) = *(const f16x8*)hv;
            *(f16x8*)(zsM + off) = *(const f16x8*)mv;
        }
    }

    float z2r[2][4];
    #pragma unroll
    for (int m = 0; m < 2; ++m)
        #pragma unroll
        for (int r = 0; r < 4; ++r)
            z2r[m][r] = z2w[nb + m * 16 + lg * 4 + r];

    float bestv[2][4];
    int   besti[2][4];
    #pragma unroll
    for (int m = 0; m < 2; ++m)
        #pragma unroll
        for (int r = 0; r < 4; ++r) { bestv[m][r] = INFINITY; besti[m][r] = 0; }

    // B register double-buffer: prefetch chunk 0 (before barrier; latency hides under z-build)
    f16x8 bhA[2], bmA[2], bhB[2], bmB[2];
    #pragma unroll
    for (int n = 0; n < 2; ++n) {
        bhA[n] = *(const f16x8*)(img + boff[n]);
        bmA[n] = *(const f16x8*)(img + 16384 + boff[n]);
    }

    __syncthreads();   // z planes published

    // A register double-buffer: prefetch ch 0 fragments (after barrier; z-LDS now valid)
    f16x8 ahA[2], amA[2], ahB[2], amB[2];
    #pragma unroll
    for (int m = 0; m < 2; ++m) {
        const int q = m * 16 + l15;
        const int off = (q * 512 + (lg * 8) * 2) ^ ((q & 7) << 4);
        ahA[m] = *(const f16x8*)(zsH + off);
        amA[m] = *(const f16x8*)(zsM + off);
    }

// phase: issue B(t+1)->NXT B regs, issue A((ch+1)&7)->NXT A regs (z static: wraps exactly),
// then MFMA on CUR regs loaded last phase. Operands/order bit-identical to rounds 3-10.
#define PHASE(CH, CAH, CAM, NAH, NAM, CBH, CBM, NBH, NBM)                                  \
    {                                                                                      \
        const int t  = kt * 8 + (CH);                                                      \
        const int tn = (t + 1 < NCH) ? (t + 1) : 0;                                        \
        const char* nbase = img + (size_t)tn * CHB;                                        \
        _Pragma("unroll")                                                                  \
        for (int n = 0; n < 2; ++n) {                                                      \
            NBH[n] = *(const f16x8*)(nbase + boff[n]);                                     \
            NBM[n] = *(const f16x8*)(nbase + 16384 + boff[n]);                             \
        }                                                                                  \
        const int chn = ((CH) + 1) & 7;                                                    \
        _Pragma("unroll")                                                                  \
        for (int m = 0; m < 2; ++m) {                                                      \
            const int q = m * 16 + l15;                                                    \
            const int off = (q * 512 + (chn * 32 + lg * 8) * 2) ^ ((q & 7) << 4);          \
            NAH[m] = *(const f16x8*)(zsH + off);                                           \
            NAM[m] = *(const f16x8*)(zsM + off);                                           \
        }                                                                                  \
        __builtin_amdgcn_s_setprio(1);                                                     \
        _Pragma("unroll")                                                                  \
        for (int m = 0; m < 2; ++m)                                                        \
            _Pragma("unroll")                                                              \
            for (int n = 0; n < 2; ++n) {                                                  \
                a1[m][n] = __builtin_amdgcn_mfma_f32_16x16x32_f16(CAH[m], CBH[n], a1[m][n], 0, 0, 0); \
                a2[m][n] = __builtin_amdgcn_mfma_f32_16x16x32_f16(CAH[m], CBM[n], a2[m][n], 0, 0, 0); \
                a2[m][n] = __builtin_amdgcn_mfma_f32_16x16x32_f16(CAM[m], CBH[n], a2[m][n], 0, 0, 0); \
                a3[m][n] = __builtin_amdgcn_mfma_f32_16x16x32_f16(CAM[m], CBM[n], a3[m][n], 0, 0, 0); \
            }                                                                              \
        __builtin_amdgcn_s_setprio(0);                                                     \
    }

    for (int kt = 0; kt < NKT; ++kt) {
        f32x4 a1[2][2], a2[2][2], a3[2][2];
        const f32x4 vz = {0.0f, 0.0f, 0.0f, 0.0f};
        #pragma unroll
        for (int m = 0; m < 2; ++m)
            #pragma unroll
            for (int n = 0; n < 2; ++n) { a1[m][n] = vz; a2[m][n] = vz; a3[m][n] = vz; }

        float e2v[2];
        #pragma unroll
        for (int n = 0; n < 2; ++n)
            e2v[n] = e2w[kt * 256 + w * 32 + n * 16 + l15];

        PHASE(0, ahA, amA, ahB, amB, bhA, bmA, bhB, bmB)
        PHASE(1, ahB, amB, ahA, amA, bhB, bmB, bhA, bmA)
        PHASE(2, ahA, amA, ahB, amB, bhA, bmA, bhB, bmB)
        PHASE(3, ahB, amB, ahA, amA, bhB, bmB, bhA, bmA)
        PHASE(4, ahA, amA, ahB, amB, bhA, bmA, bhB, bmB)
        PHASE(5, ahB, amB, ahA, amA, bhB, bmB, bhA, bmA)
        PHASE(6, ahA, amA, ahB, amB, bhA, bmA, bhB, bmB)
        PHASE(7, ahB, amB, ahA, amA, bhB, bmB, bhA, bmA)

        // ---- per-k-tile score + argmin (bit-identical rounding to rounds 2-10) ----
        #pragma unroll
        for (int m = 0; m < 2; ++m)
            #pragma unroll
            for (int n = 0; n < 2; ++n) {
                const int code = kt * 256 + w * 32 + n * 16 + l15;
                #pragma unroll
                for (int r = 0; r < 4; ++r) {
                    float rr = fmaf(a3[m][n][r], 0x1p-11f, a2[m][n][r]);
                    rr = fmaf(rr, 0x1p-11f, a1[m][n][r]);           // dot * 2^13
                    float tt = fmaf(rr, -0x1p-12f, z2r[m][r]);      // = fl(z2 - 2*dot), single round
                    float s  = __fadd_rn(tt, e2v[n]);
                    if (s < bestv[m][r]) { bestv[m][r] = s; besti[m][r] = code; }
                }
            }

        // PACING barrier every 2 k-tiles (round-9 verified: bounds drift, L2 stream hot).
        if (kt & 1) __builtin_amdgcn_s_barrier();
    }
#undef PHASE

    // ---- cross-lane argmin within each 16-lane column group ----
    #pragma unroll
    for (int m = 0; m < 2; ++m)
        #pragma unroll
        for (int r = 0; r < 4; ++r) {
            float v = bestv[m][r]; int idx = besti[m][r];
            #pragma unroll
            for (int dlt = 1; dlt < 16; dlt <<= 1) {
                float v2 = __shfl_xor(v, dlt, 64);
                int   i2 = __shfl_xor(idx, dlt, 64);
                if (v2 < v || (v2 == v && i2 < idx)) { v = v2; idx = i2; }
            }
            if (l15 == 0) {
                const int q = m * 16 + lg * 4 + r;   // 0..31
                redv[w][q] = v; redi[w][q] = idx;
            }
        }
    __syncthreads();
    if (tid < QT) {
        float bv = redv[0][tid]; int bi = redi[0][tid];
        #pragma unroll
        for (int ww = 1; ww < 8; ++ww) {
            float v = redv[ww][tid]; int ii = redi[ww][tid];
            if (v < bv || (v == bv && ii < bi)) { bv = v; bi = ii; }
        }
        bidx[tid] = bi;
        out1[nb + tid] = (float)bi;
    }
    __syncthreads();

    // ---- fused epilogue: quantized_st + commit-loss partial (float4 erow reads) ----
    {
        const int q = tid & 31, dg = tid >> 5;    // dg 0..15 -> 16 consecutive d
        const int myidx = bidx[q];
        const float* erow = emb + (size_t)myidx * 256;
        float lsum = 0.0f;
        #pragma unroll
        for (int g = 0; g < 4; ++g) {
            const int d0 = dg * 16 + g * 4;
            float4 qv4 = *(const float4*)(erow + d0);
            #pragma unroll
            for (int j = 0; j < 4; ++j) {
                const int d = d0 + j;
                const size_t gi = (size_t)(b * 256 + d) * 1024 + hw0 + q;
                float zv = z[gi];
                float qv = (&qv4.x)[j];
                out0[gi] = zv + (qv - zv);
                float e = zv - qv;
                lsum += e * e;
            }
        }
        #pragma unroll
        for (int off = 32; off > 0; off >>= 1) lsum += __shfl_down(lsum, off, 64);
        if (lane == 0) wsum[w] = lsum;
        __syncthreads();
        if (tid == 0) {
            float s = 0.0f;
            #pragma unroll
            for (int i = 0; i < 8; ++i) s += wsum[i];
            atomicAdd(loss_accum, s);
        }
    }
}

__global__ void loss_final(const float* __restrict__ loss_accum, float* __restrict__ out2) {
    out2[0] = loss_accum[0] * (1.0f / 4194304.0f);
}

extern "C" void kernel_launch(void* const* d_in, const int* in_sizes, int n_in,
                              void* d_out, int out_size, void* d_ws, size_t ws_size,
                              hipStream_t stream) {
    (void)in_sizes; (void)n_in; (void)out_size; (void)ws_size;
    const float* z   = (const float*)d_in[0];   // (16,256,32,32)
    const float* emb = (const float*)d_in[1];   // (8192,256)
    float* ws_f = (float*)d_ws;
    char*  wsb  = (char*)d_ws;
    float* loss = ws_f;                          // [0]
    float* e2   = ws_f + 64;                     // 8192 f32
    float* z2   = ws_f + 64 + KCODES;            // 16384 f32
    char*  img  = wsb + 131072;                  // 8 MB fp16-plane image
    float* out0 = (float*)d_out;                 // quantized_st: 4,194,304
    float* out1 = out0 + (size_t)4194304;        // indices:      16,384
    float* out2 = out1 + (size_t)16384;          // commit_loss:  1

    esplit_kernel<<<KCODES, 256, 0, stream>>>(emb, img, e2);
    z2_kernel<<<NTOT / 256, 256, 0, stream>>>(z, z2, loss);
    vq_main<<<NTOT / QT, 512, 0, stream>>>(z, emb, e2, z2, img, loss, out0, out1);
    loss_final<<<1, 1, 0, stream>>>(loss, out2);
}

// Round 12
// 236.809 us; speedup vs baseline: 1.5245x; 1.1314x over previous
//
#include <hip/hip_runtime.h>
#include <math.h>

typedef _Float16 f16;
typedef _Float16 f16x8 __attribute__((ext_vector_type(8)));
typedef float f32x4 __attribute__((ext_vector_type(4)));

#define KCODES 8192
#define DDIM   256
#define NTOT   16384
#define QT     32      // queries per block; grid 512 = 2 lockstep generations at 1 block/CU
#define NKT    32      // k-tiles of 256 codes
#define NCH    256     // total 32KB chunks = NKT*8
#define CHB    32768   // chunk image bytes: 2 planes * 256 codes * 32 d * 2B

#define F16_MIN_NORMAL 6.103515625e-05f

// ws layout: [0] loss | +256B e2[8192] f32 | z2[16384] f32 | +131072B emb-plane image (8 MB)

// z2[n]: exact (fp64) sum of fp32 squares, rounded once (rounds 2-11 verified). Also zeroes loss.
__global__ void z2_kernel(const float* __restrict__ z, float* __restrict__ z2out,
                          float* __restrict__ loss) {
    int n  = blockIdx.x * 256 + threadIdx.x;
    if (n == 0) loss[0] = 0.0f;
    int b  = n >> 10;
    int hw = n & 1023;
    const float* base = z + (size_t)b * DDIM * 1024 + hw;
    double acc = 0.0;
    #pragma unroll 8
    for (int d = 0; d < 256; ++d) {
        float v  = base[(size_t)d * 1024];
        float sq = __fmul_rn(v, v);
        acc += (double)sq;
    }
    z2out[n] = (float)acc;
}

// split emb into 2 fp16 planes (pre-scaled by 2^13) as the swizzled image; fused e2.
// Image layout bit-identical to rounds 3-11.
__global__ void esplit_kernel(const float* __restrict__ emb, char* __restrict__ img,
                              float* __restrict__ e2out) {
    __shared__ double part[4];
    int c = blockIdx.x, d = threadIdx.x;
    float ev = emb[(size_t)c * 256 + d];
    double sq = (double)__fmul_rn(ev, ev);
    #pragma unroll
    for (int off = 32; off > 0; off >>= 1) sq += __shfl_down(sq, off, 64);
    if ((d & 63) == 0) part[d >> 6] = sq;
    __syncthreads();
    if (d == 0) e2out[c] = (float)(part[0] + part[1] + part[2] + part[3]);
    float e = ev * 8192.0f;                               // exact pow2 scale
    float eh = 0.0f;
    if (fabsf(e) >= F16_MIN_NORMAL) eh = (float)(f16)e;   // normal-or-zero hi plane
    f16 ehh = (f16)eh;
    f16 emm = (f16)((e - eh) * 2048.0f);                  // residual scaled 2^11
    int kt = c >> 8, ch = d >> 5, ci = c & 255, dp = d & 31;
    char* p = img + (size_t)(kt * 8 + ch) * CHB;
    int off2 = (ci * 64 + dp * 2) ^ ((ci & 7) << 4);      // XOR swizzle (bits 4-6)
    *(f16*)(p + off2) = ehh;
    *(f16*)(p + 16384 + off2) = emm;
}

// Round-11 structure (QT=32, 8 waves, LDS-capped 1 block/CU, A+B register double-buffers,
// pacing barrier every 2 k-tiles). NEW: 3-term split — the mm-plane MFMA (a3) is dropped;
// its contribution to dot is ~1.5e-10 RMS (a3*2^-35), same order as the already-accepted
// MFMA-vs-np deviation. 12 MFMA/phase/wave instead of 16.
__launch_bounds__(512, 2)
__global__ void vq_main(const float* __restrict__ z, const float* __restrict__ emb,
                        const float* __restrict__ e2w, const float* __restrict__ z2w,
                        const char* __restrict__ img, float* __restrict__ loss_accum,
                        float* __restrict__ out0, float* __restrict__ out1) {
    // 41 KB per plane (only first 16 KB used) -> 86 KB/block -> 1 block/CU occupancy cap
    __shared__ __align__(16) char zsH[41984];     // z hi plane  [32 q][256 d] f16, swizzled
    __shared__ __align__(16) char zsM[41984];     // z mid plane (scaled 2^11)
    __shared__ float redv[8][QT];
    __shared__ int   redi[8][QT];
    __shared__ int   bidx[QT];
    __shared__ float wsum[8];

    const int tid  = threadIdx.x;
    const int w    = tid >> 6;
    const int lane = tid & 63;
    const int l15  = lane & 15;
    const int lg   = lane >> 4;
    const int nb   = blockIdx.x * QT;
    const int b    = nb >> 10;
    const int hw0  = nb & 1023;

    // per-lane B read offsets (fixed per chunk; same formula as rounds 3-11)
    int boff[2];
    #pragma unroll
    for (int n = 0; n < 2; ++n) {
        const int c = w * 32 + n * 16 + l15;
        boff[n] = (c * 64 + lg * 16) ^ ((c & 7) << 4);
    }

    // ---- build z fp16 planes in LDS (b128 writes; values/offsets bit-identical) ----
    {
        const int q = tid & 31, dg = tid >> 5;    // dg 0..15 -> 16 d per thread
        #pragma unroll
        for (int g = 0; g < 2; ++g) {
            const int d0 = dg * 16 + g * 8;       // 8 consecutive d
            f16 hv[8], mv[8];
            #pragma unroll
            for (int j = 0; j < 8; ++j) {
                float zv = z[(size_t)(b * 256 + d0 + j) * 1024 + hw0 + q];
                float zh = 0.0f;
                if (fabsf(zv) >= F16_MIN_NORMAL) zh = (float)(f16)zv;
                hv[j] = (f16)zh;
                mv[j] = (f16)((zv - zh) * 2048.0f);
            }
            const int off = (q * 512 + d0 * 2) ^ ((q & 7) << 4);  // 16B-aligned
            *(f16x8*)(zsH + off) = *(const f16x8*)hv;
            *(f16x8*)(zsM + off) = *(const f16x8*)mv;
        }
    }

    float z2r[2][4];
    #pragma unroll
    for (int m = 0; m < 2; ++m)
        #pragma unroll
        for (int r = 0; r < 4; ++r)
            z2r[m][r] = z2w[nb + m * 16 + lg * 4 + r];

    float bestv[2][4];
    int   besti[2][4];
    #pragma unroll
    for (int m = 0; m < 2; ++m)
        #pragma unroll
        for (int r = 0; r < 4; ++r) { bestv[m][r] = INFINITY; besti[m][r] = 0; }

    // B register double-buffer: prefetch chunk 0 (before barrier; latency hides under z-build)
    f16x8 bhA[2], bmA[2], bhB[2], bmB[2];
    #pragma unroll
    for (int n = 0; n < 2; ++n) {
        bhA[n] = *(const f16x8*)(img + boff[n]);
        bmA[n] = *(const f16x8*)(img + 16384 + boff[n]);
    }

    __syncthreads();   // z planes published

    // A register double-buffer: prefetch ch 0 fragments (after barrier; z-LDS now valid)
    f16x8 ahA[2], amA[2], ahB[2], amB[2];
    #pragma unroll
    for (int m = 0; m < 2; ++m) {
        const int q = m * 16 + l15;
        const int off = (q * 512 + (lg * 8) * 2) ^ ((q & 7) << 4);
        ahA[m] = *(const f16x8*)(zsH + off);
        amA[m] = *(const f16x8*)(zsM + off);
    }

// phase: issue B(t+1)->NXT B regs, issue A((ch+1)&7)->NXT A regs (z static: wraps exactly),
// then MFMA on CUR regs loaded last phase. 3 MFMA per (m,n): hh->a1, hm+mh->a2 (mm dropped).
#define PHASE(CH, CAH, CAM, NAH, NAM, CBH, CBM, NBH, NBM)                                  \
    {                                                                                      \
        const int t  = kt * 8 + (CH);                                                      \
        const int tn = (t + 1 < NCH) ? (t + 1) : 0;                                        \
        const char* nbase = img + (size_t)tn * CHB;                                        \
        _Pragma("unroll")                                                                  \
        for (int n = 0; n < 2; ++n) {                                                      \
            NBH[n] = *(const f16x8*)(nbase + boff[n]);                                     \
            NBM[n] = *(const f16x8*)(nbase + 16384 + boff[n]);                             \
        }                                                                                  \
        const int chn = ((CH) + 1) & 7;                                                    \
        _Pragma("unroll")                                                                  \
        for (int m = 0; m < 2; ++m) {                                                      \
            const int q = m * 16 + l15;                                                    \
            const int off = (q * 512 + (chn * 32 + lg * 8) * 2) ^ ((q & 7) << 4);          \
            NAH[m] = *(const f16x8*)(zsH + off);                                           \
            NAM[m] = *(const f16x8*)(zsM + off);                                           \
        }                                                                                  \
        __builtin_amdgcn_s_setprio(1);                                                     \
        _Pragma("unroll")                                                                  \
        for (int m = 0; m < 2; ++m)                                                        \
            _Pragma("unroll")                                                              \
            for (int n = 0; n < 2; ++n) {                                                  \
                a1[m][n] = __builtin_amdgcn_mfma_f32_16x16x32_f16(CAH[m], CBH[n], a1[m][n], 0, 0, 0); \
                a2[m][n] = __builtin_amdgcn_mfma_f32_16x16x32_f16(CAH[m], CBM[n], a2[m][n], 0, 0, 0); \
                a2[m][n] = __builtin_amdgcn_mfma_f32_16x16x32_f16(CAM[m], CBH[n], a2[m][n], 0, 0, 0); \
            }                                                                              \
        __builtin_amdgcn_s_setprio(0);                                                     \
    }

    for (int kt = 0; kt < NKT; ++kt) {
        f32x4 a1[2][2], a2[2][2];
        const f32x4 vz = {0.0f, 0.0f, 0.0f, 0.0f};
        #pragma unroll
        for (int m = 0; m < 2; ++m)
            #pragma unroll
            for (int n = 0; n < 2; ++n) { a1[m][n] = vz; a2[m][n] = vz; }

        float e2v[2];
        #pragma unroll
        for (int n = 0; n < 2; ++n)
            e2v[n] = e2w[kt * 256 + w * 32 + n * 16 + l15];

        PHASE(0, ahA, amA, ahB, amB, bhA, bmA, bhB, bmB)
        PHASE(1, ahB, amB, ahA, amA, bhB, bmB, bhA, bmA)
        PHASE(2, ahA, amA, ahB, amB, bhA, bmA, bhB, bmB)
        PHASE(3, ahB, amB, ahA, amA, bhB, bmB, bhA, bmA)
        PHASE(4, ahA, amA, ahB, amB, bhA, bmA, bhB, bmB)
        PHASE(5, ahB, amB, ahA, amA, bhB, bmB, bhA, bmA)
        PHASE(6, ahA, amA, ahB, amB, bhA, bmA, bhB, bmB)
        PHASE(7, ahB, amB, ahA, amA, bhB, bmB, bhA, bmA)

        // ---- per-k-tile score + argmin ----
        // dot*2^13 = a1 + a2*2^-11 (mm term dropped: ~1.5e-10 RMS in dot, below the
        // accepted deviation). Critical single-rounding fl(z2 - 2*dot) fma preserved.
        #pragma unroll
        for (int m = 0; m < 2; ++m)
            #pragma unroll
            for (int n = 0; n < 2; ++n) {
                const int code = kt * 256 + w * 32 + n * 16 + l15;
                #pragma unroll
                for (int r = 0; r < 4; ++r) {
                    float rr = fmaf(a2[m][n][r], 0x1p-11f, a1[m][n][r]);   // dot * 2^13
                    float tt = fmaf(rr, -0x1p-12f, z2r[m][r]);             // = fl(z2 - 2*dot)
                    float s  = __fadd_rn(tt, e2v[n]);
                    if (s < bestv[m][r]) { bestv[m][r] = s; besti[m][r] = code; }
                }
            }

        // PACING barrier every 2 k-tiles (rounds 9/11 verified: bounds drift, L2 stream hot).
        if (kt & 1) __builtin_amdgcn_s_barrier();
    }
#undef PHASE

    // ---- cross-lane argmin within each 16-lane column group ----
    #pragma unroll
    for (int m = 0; m < 2; ++m)
        #pragma unroll
        for (int r = 0; r < 4; ++r) {
            float v = bestv[m][r]; int idx = besti[m][r];
            #pragma unroll
            for (int dlt = 1; dlt < 16; dlt <<= 1) {
                float v2 = __shfl_xor(v, dlt, 64);
                int   i2 = __shfl_xor(idx, dlt, 64);
                if (v2 < v || (v2 == v && i2 < idx)) { v = v2; idx = i2; }
            }
            if (l15 == 0) {
                const int q = m * 16 + lg * 4 + r;   // 0..31
                redv[w][q] = v; redi[w][q] = idx;
            }
        }
    __syncthreads();
    if (tid < QT) {
        float bv = redv[0][tid]; int bi = redi[0][tid];
        #pragma unroll
        for (int ww = 1; ww < 8; ++ww) {
            float v = redv[ww][tid]; int ii = redi[ww][tid];
            if (v < bv || (v == bv && ii < bi)) { bv = v; bi = ii; }
        }
        bidx[tid] = bi;
        out1[nb + tid] = (float)bi;
    }
    __syncthreads();

    // ---- fused epilogue: quantized_st + commit-loss partial (float4 erow reads) ----
    {
        const int q = tid & 31, dg = tid >> 5;    // dg 0..15 -> 16 consecutive d
        const int myidx = bidx[q];
        const float* erow = emb + (size_t)myidx * 256;
        float lsum = 0.0f;
        #pragma unroll
        for (int g = 0; g < 4; ++g) {
            const int d0 = dg * 16 + g * 4;
            float4 qv4 = *(const float4*)(erow + d0);
            #pragma unroll
            for (int j = 0; j < 4; ++j) {
                const int d = d0 + j;
                const size_t gi = (size_t)(b * 256 + d) * 1024 + hw0 + q;
                float zv = z[gi];
                float qv = (&qv4.x)[j];
                out0[gi] = zv + (qv - zv);
                float e = zv - qv;
                lsum += e * e;
            }
        }
        #pragma unroll
        for (int off = 32; off > 0; off >>= 1) lsum += __shfl_down(lsum, off, 64);
        if (lane == 0) wsum[w] = lsum;
        __syncthreads();
        if (tid == 0) {
            float s = 0.0f;
            #pragma unroll
            for (int i = 0; i < 8; ++i) s += wsum[i];
            atomicAdd(loss_accum, s);
        }
    }
}

__global__ void loss_final(const float* __restrict__ loss_accum, float* __restrict__ out2) {
    out2[0] = loss_accum[0] * (1.0f / 4194304.0f);
}

extern "C" void kernel_launch(void* const* d_in, const int* in_sizes, int n_in,
                              void* d_out, int out_size, void* d_ws, size_t ws_size,
                              hipStream_t stream) {
    (void)in_sizes; (void)n_in; (void)out_size; (void)ws_size;
    const float* z   = (const float*)d_in[0];   // (16,256,32,32)
    const float* emb = (const float*)d_in[1];   // (8192,256)
    float* ws_f = (float*)d_ws;
    char*  wsb  = (char*)d_ws;
    float* loss = ws_f;                          // [0]
    float* e2   = ws_f + 64;                     // 8192 f32
    float* z2   = ws_f + 64 + KCODES;            // 16384 f32
    char*  img  = wsb + 131072;                  // 8 MB fp16-plane image
    float* out0 = (float*)d_out;                 // quantized_st: 4,194,304
    float* out1 = out0 + (size_t)4194304;        // indices:      16,384
    float* out2 = out1 + (size_t)16384;          // commit_loss:  1

    esplit_kernel<<<KCODES, 256, 0, stream>>>(emb, img, e2);
    z2_kernel<<<NTOT / 256, 256, 0, stream>>>(z, z2, loss);
    vq_main<<<NTOT / QT, 512, 0, stream>>>(z, emb, e2, z2, img, loss, out0, out1);
    loss_final<<<1, 1, 0, stream>>>(loss, out2);
}

// Round 13
// 232.911 us; speedup vs baseline: 1.5500x; 1.0167x over previous
//
#include <hip/hip_runtime.h>
#include <math.h>

typedef _Float16 f16;
typedef _Float16 f16x8 __attribute__((ext_vector_type(8)));
typedef float f32x4 __attribute__((ext_vector_type(4)));

#define KCODES 8192
#define DDIM   256
#define NTOT   16384
#define QT     32      // queries per block; grid 512 = 2 lockstep generations at 1 block/CU
#define NKT    32      // k-tiles of 256 codes
#define NCH    256     // total 32KB chunks = NKT*8
#define CHB    32768   // chunk image bytes: 2 planes * 256 codes * 32 d * 2B

#define F16_MIN_NORMAL 6.103515625e-05f

// ws layout: [0] loss | +256B e2[8192] f32 | z2[16384] f32 | +131072B emb-plane image (8 MB)

// z2[n]: exact (fp64) sum of fp32 squares, rounded once (rounds 2-12 verified). Also zeroes loss.
__global__ void z2_kernel(const float* __restrict__ z, float* __restrict__ z2out,
                          float* __restrict__ loss) {
    int n  = blockIdx.x * 256 + threadIdx.x;
    if (n == 0) loss[0] = 0.0f;
    int b  = n >> 10;
    int hw = n & 1023;
    const float* base = z + (size_t)b * DDIM * 1024 + hw;
    double acc = 0.0;
    #pragma unroll 8
    for (int d = 0; d < 256; ++d) {
        float v  = base[(size_t)d * 1024];
        float sq = __fmul_rn(v, v);
        acc += (double)sq;
    }
    z2out[n] = (float)acc;
}

// split emb into 2 fp16 planes (pre-scaled by 2^13) as the swizzled image; fused e2.
// Image layout bit-identical to rounds 3-12.
__global__ void esplit_kernel(const float* __restrict__ emb, char* __restrict__ img,
                              float* __restrict__ e2out) {
    __shared__ double part[4];
    int c = blockIdx.x, d = threadIdx.x;
    float ev = emb[(size_t)c * 256 + d];
    double sq = (double)__fmul_rn(ev, ev);
    #pragma unroll
    for (int off = 32; off > 0; off >>= 1) sq += __shfl_down(sq, off, 64);
    if ((d & 63) == 0) part[d >> 6] = sq;
    __syncthreads();
    if (d == 0) e2out[c] = (float)(part[0] + part[1] + part[2] + part[3]);
    float e = ev * 8192.0f;                               // exact pow2 scale
    float eh = 0.0f;
    if (fabsf(e) >= F16_MIN_NORMAL) eh = (float)(f16)e;   // normal-or-zero hi plane
    f16 ehh = (f16)eh;
    f16 emm = (f16)((e - eh) * 2048.0f);                  // residual scaled 2^11
    int kt = c >> 8, ch = d >> 5, ci = c & 255, dp = d & 31;
    char* p = img + (size_t)(kt * 8 + ch) * CHB;
    int off2 = (ci * 64 + dp * 2) ^ ((ci & 7) << 4);      // XOR swizzle (bits 4-6)
    *(f16*)(p + off2) = ehh;
    *(f16*)(p + 16384 + off2) = emm;
}

// Round-12 structure + T15 double-pipeline: group(kt) accumulates into one acc set while
// the 16 score computations of kt-1 run 2-per-phase inside kt's phases (score VALU hides
// under the MFMA shadow). A-LDS offsets precomputed (aoffs[8][2]). Numerics bit-identical:
// same ops, same order, same rounding, same bestv update sequence.
__launch_bounds__(512, 2)
__global__ void vq_main(const float* __restrict__ z, const float* __restrict__ emb,
                        const float* __restrict__ e2w, const float* __restrict__ z2w,
                        const char* __restrict__ img, float* __restrict__ loss_accum,
                        float* __restrict__ out0, float* __restrict__ out1) {
    // 41 KB per plane (only first 16 KB used) -> 86 KB/block -> 1 block/CU occupancy cap
    __shared__ __align__(16) char zsH[41984];     // z hi plane  [32 q][256 d] f16, swizzled
    __shared__ __align__(16) char zsM[41984];     // z mid plane (scaled 2^11)
    __shared__ float redv[8][QT];
    __shared__ int   redi[8][QT];
    __shared__ int   bidx[QT];
    __shared__ float wsum[8];

    const int tid  = threadIdx.x;
    const int w    = tid >> 6;
    const int lane = tid & 63;
    const int l15  = lane & 15;
    const int lg   = lane >> 4;
    const int nb   = blockIdx.x * QT;
    const int b    = nb >> 10;
    const int hw0  = nb & 1023;

    // per-lane B read offsets (fixed per chunk; same formula as rounds 3-12)
    int boff[2];
    #pragma unroll
    for (int n = 0; n < 2; ++n) {
        const int c = w * 32 + n * 16 + l15;
        boff[n] = (c * 64 + lg * 16) ^ ((c & 7) << 4);
    }
    // precomputed A-LDS offsets per (ch, m) — kills per-phase v_add/v_xor addressing
    int aoffs[8][2];
    #pragma unroll
    for (int ch = 0; ch < 8; ++ch)
        #pragma unroll
        for (int m = 0; m < 2; ++m) {
            const int q = m * 16 + l15;
            aoffs[ch][m] = (q * 512 + (ch * 32 + lg * 8) * 2) ^ ((q & 7) << 4);
        }

    // ---- build z fp16 planes in LDS (b128 writes; values/offsets bit-identical) ----
    {
        const int q = tid & 31, dg = tid >> 5;    // dg 0..15 -> 16 d per thread
        #pragma unroll
        for (int g = 0; g < 2; ++g) {
            const int d0 = dg * 16 + g * 8;       // 8 consecutive d
            f16 hv[8], mv[8];
            #pragma unroll
            for (int j = 0; j < 8; ++j) {
                float zv = z[(size_t)(b * 256 + d0 + j) * 1024 + hw0 + q];
                float zh = 0.0f;
                if (fabsf(zv) >= F16_MIN_NORMAL) zh = (float)(f16)zv;
                hv[j] = (f16)zh;
                mv[j] = (f16)((zv - zh) * 2048.0f);
            }
            const int off = (q * 512 + d0 * 2) ^ ((q & 7) << 4);  // 16B-aligned
            *(f16x8*)(zsH + off) = *(const f16x8*)hv;
            *(f16x8*)(zsM + off) = *(const f16x8*)mv;
        }
    }

    float z2r[2][4];
    #pragma unroll
    for (int m = 0; m < 2; ++m)
        #pragma unroll
        for (int r = 0; r < 4; ++r)
            z2r[m][r] = z2w[nb + m * 16 + lg * 4 + r];

    float bestv[2][4];
    int   besti[2][4];
    #pragma unroll
    for (int m = 0; m < 2; ++m)
        #pragma unroll
        for (int r = 0; r < 4; ++r) { bestv[m][r] = INFINITY; besti[m][r] = 0; }

    // B register double-buffer: prefetch chunk 0 (before barrier; latency hides under z-build)
    f16x8 bhA[2], bmA[2], bhB[2], bmB[2];
    #pragma unroll
    for (int n = 0; n < 2; ++n) {
        bhA[n] = *(const f16x8*)(img + boff[n]);
        bmA[n] = *(const f16x8*)(img + 16384 + boff[n]);
    }

    __syncthreads();   // z planes published

    // A register double-buffer: prefetch ch 0 fragments (after barrier; z-LDS now valid)
    f16x8 ahA[2], amA[2], ahB[2], amB[2];
    #pragma unroll
    for (int m = 0; m < 2; ++m) {
        ahA[m] = *(const f16x8*)(zsH + aoffs[0][m]);
        amA[m] = *(const f16x8*)(zsM + aoffs[0][m]);
    }

    // two accumulator sets (T15): group kt fills one while scores(kt-1) drain the other
    f32x4 accA1[2][2], accA2[2][2], accB1[2][2], accB2[2][2];
    float e2vA[2], e2vB[2];
    const f32x4 vzero = {0.0f, 0.0f, 0.0f, 0.0f};

// phase: issue B(t+1)->NXT B regs, issue A((ch+1)&7)->NXT A regs, optionally compute 2
// deferred scores (items 2*CH, 2*CH+1) of kt-1 from the OTHER acc set, then MFMA on CUR.
#define PHASE(KT, CH, AC1, AC2, CAH, CAM, NAH, NAM, CBH, CBM, NBH, NBM, PA1, PA2, PE2, DOSC) \
    {                                                                                      \
        const int t  = (KT) * 8 + (CH);                                                    \
        const int tn = (t + 1 < NCH) ? (t + 1) : 0;                                        \
        const char* nbase = img + (size_t)tn * CHB;                                        \
        _Pragma("unroll")                                                                  \
        for (int n = 0; n < 2; ++n) {                                                      \
            NBH[n] = *(const f16x8*)(nbase + boff[n]);                                     \
            NBM[n] = *(const f16x8*)(nbase + 16384 + boff[n]);                             \
        }                                                                                  \
        _Pragma("unroll")                                                                  \
        for (int m = 0; m < 2; ++m) {                                                      \
            NAH[m] = *(const f16x8*)(zsH + aoffs[((CH) + 1) & 7][m]);                      \
            NAM[m] = *(const f16x8*)(zsM + aoffs[((CH) + 1) & 7][m]);                      \
        }                                                                                  \
        if (DOSC) {                                                                        \
            _Pragma("unroll")                                                              \
            for (int it = 2 * (CH); it < 2 * (CH) + 2; ++it) {                             \
                const int m = it >> 3, n = (it >> 2) & 1, r = it & 3;                      \
                const int code = ((KT) - 1) * 256 + w * 32 + n * 16 + l15;                 \
                float rr = fmaf(PA2[m][n][r], 0x1p-11f, PA1[m][n][r]);                     \
                float tt = fmaf(rr, -0x1p-12f, z2r[m][r]);                                 \
                float s  = __fadd_rn(tt, PE2[n]);                                          \
                if (s < bestv[m][r]) { bestv[m][r] = s; besti[m][r] = code; }              \
            }                                                                              \
        }                                                                                  \
        __builtin_amdgcn_s_setprio(1);                                                     \
        _Pragma("unroll")                                                                  \
        for (int m = 0; m < 2; ++m)                                                        \
            _Pragma("unroll")                                                              \
            for (int n = 0; n < 2; ++n) {                                                  \
                AC1[m][n] = __builtin_amdgcn_mfma_f32_16x16x32_f16(CAH[m], CBH[n], AC1[m][n], 0, 0, 0); \
                AC2[m][n] = __builtin_amdgcn_mfma_f32_16x16x32_f16(CAH[m], CBM[n], AC2[m][n], 0, 0, 0); \
                AC2[m][n] = __builtin_amdgcn_mfma_f32_16x16x32_f16(CAM[m], CBH[n], AC2[m][n], 0, 0, 0); \
            }                                                                              \
        __builtin_amdgcn_s_setprio(0);                                                     \
    }

// one k-tile group: zero acc, load e2v(kt) a full group ahead of its use, run 8 phases
// (with 2 deferred scores of kt-1 per phase when DOSC)
#define GROUP(KT, AC1, AC2, E2C, PA1, PA2, PE2, DOSC)                                      \
    {                                                                                      \
        _Pragma("unroll")                                                                  \
        for (int m = 0; m < 2; ++m)                                                        \
            _Pragma("unroll")                                                              \
            for (int n = 0; n < 2; ++n) { AC1[m][n] = vzero; AC2[m][n] = vzero; }          \
        _Pragma("unroll")                                                                  \
        for (int n = 0; n < 2; ++n)                                                        \
            E2C[n] = e2w[(KT) * 256 + w * 32 + n * 16 + l15];                              \
        PHASE(KT, 0, AC1, AC2, ahA, amA, ahB, amB, bhA, bmA, bhB, bmB, PA1, PA2, PE2, DOSC) \
        PHASE(KT, 1, AC1, AC2, ahB, amB, ahA, amA, bhB, bmB, bhA, bmA, PA1, PA2, PE2, DOSC) \
        PHASE(KT, 2, AC1, AC2, ahA, amA, ahB, amB, bhA, bmA, bhB, bmB, PA1, PA2, PE2, DOSC) \
        PHASE(KT, 3, AC1, AC2, ahB, amB, ahA, amA, bhB, bmB, bhA, bmA, PA1, PA2, PE2, DOSC) \
        PHASE(KT, 4, AC1, AC2, ahA, amA, ahB, amB, bhA, bmA, bhB, bmB, PA1, PA2, PE2, DOSC) \
        PHASE(KT, 5, AC1, AC2, ahB, amB, ahA, amA, bhB, bmB, bhA, bmA, PA1, PA2, PE2, DOSC) \
        PHASE(KT, 6, AC1, AC2, ahA, amA, ahB, amB, bhA, bmA, bhB, bmB, PA1, PA2, PE2, DOSC) \
        PHASE(KT, 7, AC1, AC2, ahB, amB, ahA, amA, bhB, bmB, bhA, bmA, PA1, PA2, PE2, DOSC) \
    }

    GROUP(0, accA1, accA2, e2vA, accB1, accB2, e2vB, 0)   // peel: no scores yet
    for (int ktp = 0; ktp < 15; ++ktp) {
        const int k1 = 2 * ktp + 1;
        GROUP(k1,     accB1, accB2, e2vB, accA1, accA2, e2vA, 1)  // scores kt=k1-1
        __builtin_amdgcn_s_barrier();                             // pacing every 2 kt
        GROUP(k1 + 1, accA1, accA2, e2vA, accB1, accB2, e2vB, 1)  // scores kt=k1
    }
    GROUP(31, accB1, accB2, e2vB, accA1, accA2, e2vA, 1)          // scores kt=30
    __builtin_amdgcn_s_barrier();
#undef PHASE
#undef GROUP

    // ---- tail: scores for kt=31 (same ops/order as the in-phase scores) ----
    #pragma unroll
    for (int m = 0; m < 2; ++m)
        #pragma unroll
        for (int n = 0; n < 2; ++n) {
            const int code = 31 * 256 + w * 32 + n * 16 + l15;
            #pragma unroll
            for (int r = 0; r < 4; ++r) {
                float rr = fmaf(accB2[m][n][r], 0x1p-11f, accB1[m][n][r]);
                float tt = fmaf(rr, -0x1p-12f, z2r[m][r]);
                float s  = __fadd_rn(tt, e2vB[n]);
                if (s < bestv[m][r]) { bestv[m][r] = s; besti[m][r] = code; }
            }
        }

    // ---- cross-lane argmin within each 16-lane column group ----
    #pragma unroll
    for (int m = 0; m < 2; ++m)
        #pragma unroll
        for (int r = 0; r < 4; ++r) {
            float v = bestv[m][r]; int idx = besti[m][r];
            #pragma unroll
            for (int dlt = 1; dlt < 16; dlt <<= 1) {
                float v2 = __shfl_xor(v, dlt, 64);
                int   i2 = __shfl_xor(idx, dlt, 64);
                if (v2 < v || (v2 == v && i2 < idx)) { v = v2; idx = i2; }
            }
            if (l15 == 0) {
                const int q = m * 16 + lg * 4 + r;   // 0..31
                redv[w][q] = v; redi[w][q] = idx;
            }
        }
    __syncthreads();
    if (tid < QT) {
        float bv = redv[0][tid]; int bi = redi[0][tid];
        #pragma unroll
        for (int ww = 1; ww < 8; ++ww) {
            float v = redv[ww][tid]; int ii = redi[ww][tid];
            if (v < bv || (v == bv && ii < bi)) { bv = v; bi = ii; }
        }
        bidx[tid] = bi;
        out1[nb + tid] = (float)bi;
    }
    __syncthreads();

    // ---- fused epilogue: quantized_st + commit-loss partial (float4 erow reads) ----
    {
        const int q = tid & 31, dg = tid >> 5;    // dg 0..15 -> 16 consecutive d
        const int myidx = bidx[q];
        const float* erow = emb + (size_t)myidx * 256;
        float lsum = 0.0f;
        #pragma unroll
        for (int g = 0; g < 4; ++g) {
            const int d0 = dg * 16 + g * 4;
            float4 qv4 = *(const float4*)(erow + d0);
            #pragma unroll
            for (int j = 0; j < 4; ++j) {
                const int d = d0 + j;
                const size_t gi = (size_t)(b * 256 + d) * 1024 + hw0 + q;
                float zv = z[gi];
                float qv = (&qv4.x)[j];
                out0[gi] = zv + (qv - zv);
                float e = zv - qv;
                lsum += e * e;
            }
        }
        #pragma unroll
        for (int off = 32; off > 0; off >>= 1) lsum += __shfl_down(lsum, off, 64);
        if (lane == 0) wsum[w] = lsum;
        __syncthreads();
        if (tid == 0) {
            float s = 0.0f;
            #pragma unroll
            for (int i = 0; i < 8; ++i) s += wsum[i];
            atomicAdd(loss_accum, s);
        }
    }
}

__global__ void loss_final(const float* __restrict__ loss_accum, float* __restrict__ out2) {
    out2[0] = loss_accum[0] * (1.0f / 4194304.0f);
}

extern "C" void kernel_launch(void* const* d_in, const int* in_sizes, int n_in,
                              void* d_out, int out_size, void* d_ws, size_t ws_size,
                              hipStream_t stream) {
    (void)in_sizes; (void)n_in; (void)out_size; (void)ws_size;
    const float* z   = (const float*)d_in[0];   // (16,256,32,32)
    const float* emb = (const float*)d_in[1];   // (8192,256)
    float* ws_f = (float*)d_ws;
    char*  wsb  = (char*)d_ws;
    float* loss = ws_f;                          // [0]
    float* e2   = ws_f + 64;                     // 8192 f32
    float* z2   = ws_f + 64 + KCODES;            // 16384 f32
    char*  img  = wsb + 131072;                  // 8 MB fp16-plane image
    float* out0 = (float*)d_out;                 // quantized_st: 4,194,304
    float* out1 = out0 + (size_t)4194304;        // indices:      16,384
    float* out2 = out1 + (size_t)16384;          // commit_loss:  1

    esplit_kernel<<<KCODES, 256, 0, stream>>>(emb, img, e2);
    z2_kernel<<<NTOT / 256, 256, 0, stream>>>(z, z2, loss);
    vq_main<<<NTOT / QT, 512, 0, stream>>>(z, emb, e2, z2, img, loss, out0, out1);
    loss_final<<<1, 1, 0, stream>>>(loss, out2);
}